// Round 4
// baseline (858.789 us; speedup 1.0000x reference)
//
#include <hip/hip_runtime.h>
#include <hip/hip_bf16.h>
#include <math.h>

#define NF 32
#define NH 160
#define NB 64
#define NT 256
#define NBT (NB*NT)
#define TB 32      // (b,t) rows per block in k2/k3
#define CH 64      // h-chunk staged in LDS for W2
#define LN_EPS 1e-3f

// sum across each 32-lane half of the wave (xor masks <=16 never cross halves)
__device__ __forceinline__ float half_sum(float v) {
  v += __shfl_xor(v, 1);
  v += __shfl_xor(v, 2);
  v += __shfl_xor(v, 4);
  v += __shfl_xor(v, 8);
  v += __shfl_xor(v, 16);
  return v;
}

// ---------------- kernel 1: softmax weights (B,F) ----------------
__global__ __launch_bounds__(256) void k1_weights(
    const float* __restrict__ x, const float* __restrict__ Ww,
    const float* __restrict__ bw, float* __restrict__ wout)
{
  __shared__ float red[256][NF + 1];
  __shared__ float red2[NF][8];
  const int b = blockIdx.x, tid = threadIdx.x;
  float acc[NF];
#pragma unroll
  for (int j = 0; j < NF; ++j) acc[j] = 0.f;
  const float* xb = x + (size_t)b * (NT * NF);
  for (int i = tid; i < NT * NF; i += 256) {
    const float xv = xb[i];
    const float4* wr = (const float4*)(Ww + (size_t)i * NF);
#pragma unroll
    for (int j4 = 0; j4 < NF / 4; ++j4) {
      const float4 wv = wr[j4];
      acc[4*j4+0] = fmaf(xv, wv.x, acc[4*j4+0]);
      acc[4*j4+1] = fmaf(xv, wv.y, acc[4*j4+1]);
      acc[4*j4+2] = fmaf(xv, wv.z, acc[4*j4+2]);
      acc[4*j4+3] = fmaf(xv, wv.w, acc[4*j4+3]);
    }
  }
#pragma unroll
  for (int j = 0; j < NF; ++j) red[tid][j] = acc[j];
  __syncthreads();
  {
    const int j = tid >> 3, part = tid & 7;
    float s = 0.f;
    for (int t = part; t < 256; t += 8) s += red[t][j];
    red2[j][part] = s;
  }
  __syncthreads();
  if (tid < NF) {
    float s = 0.f;
#pragma unroll
    for (int p = 0; p < 8; ++p) s += red2[tid][p];
    s += bw[tid];
    float m = s;
    m = fmaxf(m, __shfl_xor(m, 1));
    m = fmaxf(m, __shfl_xor(m, 2));
    m = fmaxf(m, __shfl_xor(m, 4));
    m = fmaxf(m, __shfl_xor(m, 8));
    m = fmaxf(m, __shfl_xor(m, 16));
    const float e = expf(s - m);
    float ssum = e;
    ssum += __shfl_xor(ssum, 1);
    ssum += __shfl_xor(ssum, 2);
    ssum += __shfl_xor(ssum, 4);
    ssum += __shfl_xor(ssum, 8);
    ssum += __shfl_xor(ssum, 16);
    wout[b * NF + tid] = e / ssum;
  }
}

// ------- kernel 2: fused per-f GRN + LN + weighted combine over f -------
// block: 256 threads = 32 kl (k-lanes) x 8 rt (row-threads); TB=32 rows.
// thread owns k in {kl+32j, j<5} x rows {rt+8q, q<4}  (20 outputs)
__global__ __launch_bounds__(256) void k2_combine(
    const float* __restrict__ x, const float* __restrict__ W1,
    const float* __restrict__ b1, const float* __restrict__ W2,
    const float* __restrict__ b2, const float* __restrict__ Wg,
    const float* __restrict__ bg, const float* __restrict__ lng,
    const float* __restrict__ lnb, const float* __restrict__ wts,
    float* __restrict__ comb)
{
  __shared__ __align__(16) float w2s[CH * NH];  // 40960 B
  __shared__ float a1s[TB * CH];                // 8192 B
  __shared__ float xs[TB * NF];                 // 4096 B
  const int tid = threadIdx.x;
  const int bt0 = blockIdx.x * TB;
  const int b = bt0 / NT;
  const int kl = tid & 31, rt = tid >> 5;

  for (int i = tid; i < TB * NF; i += 256) xs[i] = x[(size_t)bt0 * NF + i];
  __syncthreads();

  float cacc[4][5];
#pragma unroll
  for (int q = 0; q < 4; ++q)
#pragma unroll
    for (int j = 0; j < 5; ++j) cacc[q][j] = 0.f;

  for (int f = 0; f < NF; ++f) {
    float a2[4][5];
#pragma unroll
    for (int q = 0; q < 4; ++q)
#pragma unroll
      for (int j = 0; j < 5; ++j) a2[q][j] = 0.f;

    const float* W2f = W2 + (size_t)f * NH * NH;
    const float* W1f = W1 + f * NH;
    const float* b1f = b1 + f * NH;

    for (int hh = 0; hh < NH; hh += CH) {
      const int ch = (NH - hh) < CH ? (NH - hh) : CH;
      __syncthreads();  // protect LDS from previous chunk's readers
      // stage W2[f, hh:hh+ch, :] -> LDS (float4, aligned)
      {
        const float4* src = (const float4*)(W2f + hh * NH);
        float4* dst = (float4*)w2s;
        const int n4 = ch * NH / 4;
        for (int i = tid; i < n4; i += 256) dst[i] = src[i];
      }
      // compute a1 chunk: elu(x*W1+b1)
      for (int i = tid; i < TB * CH; i += 256) {
        const int row = i >> 6;      // / CH
        const int h = i & (CH - 1);
        if (h < ch) {
          const float xv = xs[row * NF + f];
          const float z = fmaf(xv, W1f[hh + h], b1f[hh + h]);
          a1s[i] = z > 0.f ? z : expm1f(z);
        }
      }
      __syncthreads();
      // a2[k] += sum_h a1[row][h] * W2[f][h][k]
      for (int h = 0; h < ch; ++h) {
        float av[4];
#pragma unroll
        for (int q = 0; q < 4; ++q) av[q] = a1s[(rt + 8 * q) * CH + h];
#pragma unroll
        for (int j = 0; j < 5; ++j) {
          const float wv = w2s[h * NH + kl + 32 * j];
#pragma unroll
          for (int q = 0; q < 4; ++q) a2[q][j] = fmaf(av[q], wv, a2[q][j]);
        }
      }
    }
    // gate + layernorm over k + weighted accumulate
    const float wf = wts[b * NF + f];
#pragma unroll
    for (int q = 0; q < 4; ++q) {
      const int row = rt + 8 * q;
      const float xv = xs[row * NF + f];
      float feat[5];
      float s1 = 0.f;
#pragma unroll
      for (int j = 0; j < 5; ++j) {
        const int k = kl + 32 * j;
        const float aa = a2[q][j] + b2[f * NH + k];
        const float zg = fmaf(xv, Wg[f * NH + k], bg[f * NH + k]);
        const float g = 1.f / (1.f + expf(-zg));
        const float ft = fmaf(g, aa - xv, xv);  // g*aa + (1-g)*xv
        feat[j] = ft;
        s1 += ft;
      }
      s1 = half_sum(s1);
      const float mean = s1 * (1.f / NH);
      float s2 = 0.f;
#pragma unroll
      for (int j = 0; j < 5; ++j) {
        const float d = feat[j] - mean;
        s2 = fmaf(d, d, s2);
      }
      s2 = half_sum(s2);
      const float inv = rsqrtf(s2 * (1.f / NH) + LN_EPS);
#pragma unroll
      for (int j = 0; j < 5; ++j) {
        const int k = kl + 32 * j;
        const float ln = (feat[j] - mean) * inv * lng[f * NH + k] + lnb[f * NH + k];
        cacc[q][j] = fmaf(wf, ln, cacc[q][j]);
      }
    }
  }
#pragma unroll
  for (int q = 0; q < 4; ++q)
#pragma unroll
    for (int j = 0; j < 5; ++j)
      comb[(size_t)(bt0 + rt + 8 * q) * NH + kl + 32 * j] = cacc[q][j];
}

// ---------------- kernel 3: output GRN + LN (in-place on d_out) ----------------
__global__ __launch_bounds__(256) void k3_outgrn(
    float* io,  // combined in, out overwritten (block-local in-place)
    const float* __restrict__ oW1, const float* __restrict__ ob1,
    const float* __restrict__ oW2, const float* __restrict__ ob2,
    const float* __restrict__ oWg, const float* __restrict__ obg,
    const float* __restrict__ olng, const float* __restrict__ olnb)
{
  __shared__ float cs[TB * NH];
  __shared__ float oas[TB * NH];
  const int tid = threadIdx.x;
  const int bt0 = blockIdx.x * TB;
  const int kl = tid & 31, rt = tid >> 5;
  for (int i = tid; i < TB * NH; i += 256) cs[i] = io[(size_t)bt0 * NH + i];
  __syncthreads();

  float oga[4][5], a1a[4][5];
#pragma unroll
  for (int q = 0; q < 4; ++q)
#pragma unroll
    for (int j = 0; j < 5; ++j) { oga[q][j] = 0.f; a1a[q][j] = 0.f; }

  for (int h = 0; h < NH; ++h) {
    float cv[4];
#pragma unroll
    for (int q = 0; q < 4; ++q) cv[q] = cs[(rt + 8 * q) * NH + h];
#pragma unroll
    for (int j = 0; j < 5; ++j) {
      const float wg = oWg[h * NH + kl + 32 * j];
      const float w1 = oW1[h * NH + kl + 32 * j];
#pragma unroll
      for (int q = 0; q < 4; ++q) {
        oga[q][j] = fmaf(cv[q], wg, oga[q][j]);
        a1a[q][j] = fmaf(cv[q], w1, a1a[q][j]);
      }
    }
  }
#pragma unroll
  for (int q = 0; q < 4; ++q)
#pragma unroll
    for (int j = 0; j < 5; ++j) {
      const int k = kl + 32 * j;
      const float z = a1a[q][j] + ob1[k];
      oas[(rt + 8 * q) * NH + k] = z > 0.f ? z : expm1f(z);
    }
  __syncthreads();

  float o2a[4][5];
#pragma unroll
  for (int q = 0; q < 4; ++q)
#pragma unroll
    for (int j = 0; j < 5; ++j) o2a[q][j] = 0.f;
  for (int h = 0; h < NH; ++h) {
    float av[4];
#pragma unroll
    for (int q = 0; q < 4; ++q) av[q] = oas[(rt + 8 * q) * NH + h];
#pragma unroll
    for (int j = 0; j < 5; ++j) {
      const float w2v = oW2[h * NH + kl + 32 * j];
#pragma unroll
      for (int q = 0; q < 4; ++q) o2a[q][j] = fmaf(av[q], w2v, o2a[q][j]);
    }
  }
#pragma unroll
  for (int q = 0; q < 4; ++q) {
    const int row = rt + 8 * q;
    float feat[5];
    float s1 = 0.f;
#pragma unroll
    for (int j = 0; j < 5; ++j) {
      const int k = kl + 32 * j;
      const float oa2 = o2a[q][j] + ob2[k];
      const float zg = oga[q][j] + obg[k];
      const float g = 1.f / (1.f + expf(-zg));
      const float c = cs[row * NH + k];
      const float ft = fmaf(g, oa2 - c, c);
      feat[j] = ft;
      s1 += ft;
    }
    s1 = half_sum(s1);
    const float mean = s1 * (1.f / NH);
    float s2 = 0.f;
#pragma unroll
    for (int j = 0; j < 5; ++j) {
      const float d = feat[j] - mean;
      s2 = fmaf(d, d, s2);
    }
    s2 = half_sum(s2);
    const float inv = rsqrtf(s2 * (1.f / NH) + LN_EPS);
#pragma unroll
    for (int j = 0; j < 5; ++j) {
      const int k = kl + 32 * j;
      io[(size_t)(bt0 + row) * NH + k] =
          (feat[j] - mean) * inv * olng[k] + olnb[k];
    }
  }
}

extern "C" void kernel_launch(void* const* d_in, const int* in_sizes, int n_in,
                              void* d_out, int out_size, void* d_ws, size_t ws_size,
                              hipStream_t stream) {
  const float* x   = (const float*)d_in[0];
  const float* W1  = (const float*)d_in[1];
  const float* b1  = (const float*)d_in[2];
  const float* W2  = (const float*)d_in[3];
  const float* b2  = (const float*)d_in[4];
  const float* Wg  = (const float*)d_in[5];
  const float* bg  = (const float*)d_in[6];
  const float* lng = (const float*)d_in[7];
  const float* lnb = (const float*)d_in[8];
  const float* Ww  = (const float*)d_in[9];
  const float* bw  = (const float*)d_in[10];
  const float* oW1 = (const float*)d_in[11];
  const float* ob1 = (const float*)d_in[12];
  const float* oW2 = (const float*)d_in[13];
  const float* ob2 = (const float*)d_in[14];
  const float* oWg = (const float*)d_in[15];
  const float* obg = (const float*)d_in[16];
  const float* olng= (const float*)d_in[17];
  const float* olnb= (const float*)d_in[18];

  float* out  = (float*)d_out;
  float* wout = out + (size_t)NBT * NH;  // weights4 region of d_out

  k1_weights<<<NB, 256, 0, stream>>>(x, Ww, bw, wout);
  k2_combine<<<NBT / TB, 256, 0, stream>>>(x, W1, b1, W2, b2, Wg, bg, lng, lnb,
                                           wout, out);
  k3_outgrn<<<NBT / TB, 256, 0, stream>>>(out, oW1, ob1, oW2, ob2, oWg, obg,
                                          olng, olnb);
}

// Round 5
// 521.548 us; speedup vs baseline: 1.6466x; 1.6466x over previous
//
#include <hip/hip_runtime.h>
#include <hip/hip_bf16.h>
#include <math.h>

#define NF 32
#define NH 160
#define NB 64
#define NT 256
#define NBT (NB*NT)
#define TB 32      // (b,t) rows per block in k2/k3
#define LN_EPS 1e-3f
#define HPAD 168   // padded h-stride (bf16 elems): 336B rows -> 16B aligned, 2-way-free banks
#define W2T_FSTRIDE (NH*HPAD)   // 26880 bf16 per f

typedef __attribute__((ext_vector_type(8))) short short8;
typedef __attribute__((ext_vector_type(4))) float f32x4;

__device__ __forceinline__ unsigned short f2bf(float f) {
  __hip_bfloat16 b = __float2bfloat16(f);
  return *reinterpret_cast<unsigned short*>(&b);
}

// sum across each 32-lane half of the wave
__device__ __forceinline__ float half_sum(float v) {
  v += __shfl_xor(v, 1);
  v += __shfl_xor(v, 2);
  v += __shfl_xor(v, 4);
  v += __shfl_xor(v, 8);
  v += __shfl_xor(v, 16);
  return v;
}

// ---------------- kernel 0: W2 (f,h,k) fp32 -> W2T (f,k,h_pad) bf16 in ws ----------------
__global__ __launch_bounds__(256) void k0_w2t(
    const float* __restrict__ W2, unsigned short* __restrict__ w2t_g)
{
  __shared__ float tr[32 * 161];
  const int f = blockIdx.x, tid = threadIdx.x;
  const float* W2f = W2 + (size_t)f * NH * NH;
  unsigned short* outf = w2t_g + (size_t)f * W2T_FSTRIDE;
  for (int ht = 0; ht < 5; ++ht) {
    const int hbase = ht * 32;
    __syncthreads();
#pragma unroll
    for (int i = 0; i < 20; ++i) {
      const int idx = tid + 256 * i;           // idx = hh*160 + k
      const int hh = idx / 160, k = idx - hh * 160;
      tr[hh * 161 + k] = W2f[hbase * 160 + idx];
    }
    __syncthreads();
#pragma unroll
    for (int i = 0; i < 20; ++i) {
      const int idx = tid + 256 * i;           // idx = k*32 + hc
      const int k = idx >> 5, hc = idx & 31;
      outf[(size_t)k * HPAD + hbase + hc] = f2bf(tr[hc * 161 + k]);
    }
  }
}

// ---------------- kernel 1: softmax weights (B,F) ----------------
__global__ __launch_bounds__(256) void k1_weights(
    const float* __restrict__ x, const float* __restrict__ Ww,
    const float* __restrict__ bw, float* __restrict__ wout)
{
  __shared__ float red[256][NF + 1];
  __shared__ float red2[NF][8];
  const int b = blockIdx.x, tid = threadIdx.x;
  float acc[NF];
#pragma unroll
  for (int j = 0; j < NF; ++j) acc[j] = 0.f;
  const float* xb = x + (size_t)b * (NT * NF);
  for (int i = tid; i < NT * NF; i += 256) {
    const float xv = xb[i];
    const float4* wr = (const float4*)(Ww + (size_t)i * NF);
#pragma unroll
    for (int j4 = 0; j4 < NF / 4; ++j4) {
      const float4 wv = wr[j4];
      acc[4*j4+0] = fmaf(xv, wv.x, acc[4*j4+0]);
      acc[4*j4+1] = fmaf(xv, wv.y, acc[4*j4+1]);
      acc[4*j4+2] = fmaf(xv, wv.z, acc[4*j4+2]);
      acc[4*j4+3] = fmaf(xv, wv.w, acc[4*j4+3]);
    }
  }
#pragma unroll
  for (int j = 0; j < NF; ++j) red[tid][j] = acc[j];
  __syncthreads();
  {
    const int j = tid >> 3, part = tid & 7;
    float s = 0.f;
    for (int t = part; t < 256; t += 8) s += red[t][j];
    red2[j][part] = s;
  }
  __syncthreads();
  if (tid < NF) {
    float s = 0.f;
#pragma unroll
    for (int p = 0; p < 8; ++p) s += red2[tid][p];
    s += bw[tid];
    float m = s;
    m = fmaxf(m, __shfl_xor(m, 1));
    m = fmaxf(m, __shfl_xor(m, 2));
    m = fmaxf(m, __shfl_xor(m, 4));
    m = fmaxf(m, __shfl_xor(m, 8));
    m = fmaxf(m, __shfl_xor(m, 16));
    const float e = expf(s - m);
    float ssum = e;
    ssum += __shfl_xor(ssum, 1);
    ssum += __shfl_xor(ssum, 2);
    ssum += __shfl_xor(ssum, 4);
    ssum += __shfl_xor(ssum, 8);
    ssum += __shfl_xor(ssum, 16);
    wout[b * NF + tid] = e / ssum;
  }
}

// ------- kernel 2: MFMA per-f GRN + LN + weighted combine over f -------
// 256 thr = 4 waves; wave w: row-tile rw=w&1 (16 rows), col-half cw=w>>1 (80 k).
// mfma_f32_16x16x32_bf16: A=a1[M=16 rows][K=h], B=W2[K=h][N=k_out] read from W2T[N][K].
// C layout: col=lane&15, row=(lane>>4)*4+reg  (m89-verified).
__global__ __launch_bounds__(256) void k2_mfma(
    const float* __restrict__ x, const float* __restrict__ W1,
    const float* __restrict__ b1, const unsigned short* __restrict__ w2t_g,
    const float* __restrict__ b2, const float* __restrict__ Wg,
    const float* __restrict__ bg, const float* __restrict__ lng,
    const float* __restrict__ lnb, const float* __restrict__ wts,
    float* __restrict__ comb)
{
  __shared__ __align__(16) unsigned short w2t[NH * HPAD];     // 53760 B
  __shared__ __align__(16) unsigned char u_buf[NH * TB * 4];  // 20480 B: a1s (bf16) then at (f32, swz)
  __shared__ float xs[TB * NF];                               // 4096 B
  const int tid = threadIdx.x;
  const int l = tid & 63, w = tid >> 6;
  const int rw = w & 1, cw = w >> 1;
  const int l15 = l & 15, lg = l >> 4;
  const int kl = tid & 31, rt = tid >> 5;     // epilogue: rows rt*4+q, k = kl+32j
  const int bt0 = blockIdx.x * TB;
  const int b = bt0 >> 8;
  const int arow = tid >> 3, apo = tid & 7;   // a1 compute: row, pair-offset

  for (int i = tid; i < TB * NF; i += 256) xs[i] = x[(size_t)bt0 * NF + i];

  float cacc[4][5];
#pragma unroll
  for (int q = 0; q < 4; ++q)
#pragma unroll
    for (int j = 0; j < 5; ++j) cacc[q][j] = 0.f;

  unsigned int* a1w = (unsigned int*)u_buf;   // packed bf16 pairs, 84 words/row

  for (int f = 0; f < NF; ++f) {
    __syncthreads();  // (A) all waves done with prev-f epilogue (u_buf) / MFMA (w2t)
    // ---- stage W2T[f] -> LDS (linear b128 copy, rows pre-padded in ws) ----
    {
      const short8* src = (const short8*)(w2t_g + (size_t)f * W2T_FSTRIDE);
      short8* dst = (short8*)w2t;
      for (int i = tid; i < W2T_FSTRIDE / 8; i += 256) dst[i] = src[i];
    }
    // ---- compute a1 = elu(x*W1+b1) -> bf16 pairs in u_buf ----
    {
      const float xv = xs[arow * NF + f];
      const float* W1f = W1 + f * NH;
      const float* b1f = b1 + f * NH;
#pragma unroll
      for (int i = 0; i < 10; ++i) {
        const int p = apo + 8 * i;            // pair index 0..79
        const float2 wv = *(const float2*)(W1f + 2 * p);
        const float2 bv = *(const float2*)(b1f + 2 * p);
        float z0 = fmaf(xv, wv.x, bv.x);
        float z1 = fmaf(xv, wv.y, bv.y);
        z0 = z0 > 0.f ? z0 : expm1f(z0);
        z1 = z1 > 0.f ? z1 : expm1f(z1);
        a1w[arow * (HPAD / 2) + p] = (unsigned)f2bf(z0) | ((unsigned)f2bf(z1) << 16);
      }
    }
    __syncthreads();  // (B)
    // ---- MFMA: acc[ct] (16x16 tile ct) over 5 K-steps ----
    f32x4 acc[5] = {f32x4{0,0,0,0}, f32x4{0,0,0,0}, f32x4{0,0,0,0},
                    f32x4{0,0,0,0}, f32x4{0,0,0,0}};
    short8 af[5];
    const unsigned short* a1r = (const unsigned short*)u_buf;
#pragma unroll
    for (int hs = 0; hs < 5; ++hs)
      af[hs] = *(const short8*)(a1r + (rw * 16 + l15) * HPAD + hs * 32 + lg * 8);
#pragma unroll
    for (int ct = 0; ct < 5; ++ct) {
      const unsigned short* bbase = w2t + (cw * 80 + ct * 16 + l15) * HPAD + lg * 8;
#pragma unroll
      for (int hs = 0; hs < 5; ++hs) {
        short8 bfr = *(const short8*)(bbase + hs * 32);
        acc[ct] = __builtin_amdgcn_mfma_f32_16x16x32_bf16(af[hs], bfr, acc[ct], 0, 0, 0);
      }
    }
    __syncthreads();  // (C) all waves done reading a1s before at overwrites u_buf
    // ---- write a2 frags -> at[k][row] (XOR-swizzled) ----
#pragma unroll
    for (int ct = 0; ct < 5; ++ct) {
      const int col = cw * 80 + ct * 16 + l15;
      int byte = col * 128 + (rw * 16 + lg * 4) * 4;
      byte ^= (col & 7) << 4;
      *(f32x4*)(u_buf + byte) = acc[ct];
    }
    __syncthreads();  // (D)
    // ---- epilogue: gate + LN over k + weighted accumulate (fp32) ----
    const float wf = wts[b * NF + f];
    f32x4 a2v[5];
#pragma unroll
    for (int j = 0; j < 5; ++j) {
      const int k = kl + 32 * j;
      int byte = k * 128 + rt * 16;
      byte ^= (k & 7) << 4;
      a2v[j] = *(const f32x4*)(u_buf + byte);
    }
#pragma unroll
    for (int q = 0; q < 4; ++q) {
      const int row = rt * 4 + q;
      const float xv = xs[row * NF + f];
      float feat[5];
      float s1 = 0.f;
#pragma unroll
      for (int j = 0; j < 5; ++j) {
        const int k = kl + 32 * j;
        const float aa = a2v[j][q] + b2[f * NH + k];
        const float zg = fmaf(xv, Wg[f * NH + k], bg[f * NH + k]);
        const float g = 1.f / (1.f + expf(-zg));
        const float ft = fmaf(g, aa - xv, xv);
        feat[j] = ft;
        s1 += ft;
      }
      s1 = half_sum(s1);
      const float mean = s1 * (1.f / NH);
      float s2 = 0.f;
#pragma unroll
      for (int j = 0; j < 5; ++j) {
        const float d = feat[j] - mean;
        s2 = fmaf(d, d, s2);
      }
      s2 = half_sum(s2);
      const float inv = rsqrtf(s2 * (1.f / NH) + LN_EPS);
#pragma unroll
      for (int j = 0; j < 5; ++j) {
        const int k = kl + 32 * j;
        const float ln = (feat[j] - mean) * inv * lng[f * NH + k] + lnb[f * NH + k];
        cacc[q][j] = fmaf(wf, ln, cacc[q][j]);
      }
    }
  }
#pragma unroll
  for (int q = 0; q < 4; ++q)
#pragma unroll
    for (int j = 0; j < 5; ++j)
      comb[(size_t)(bt0 + rt * 4 + q) * NH + kl + 32 * j] = cacc[q][j];
}

// ---------------- kernel 3: output GRN + LN (in-place on d_out) ----------------
__global__ __launch_bounds__(256) void k3_outgrn(
    float* io,
    const float* __restrict__ oW1, const float* __restrict__ ob1,
    const float* __restrict__ oW2, const float* __restrict__ ob2,
    const float* __restrict__ oWg, const float* __restrict__ obg,
    const float* __restrict__ olng, const float* __restrict__ olnb)
{
  __shared__ float cs[TB * NH];
  __shared__ float oas[TB * NH];
  const int tid = threadIdx.x;
  const int bt0 = blockIdx.x * TB;
  const int kl = tid & 31, rt = tid >> 5;
  for (int i = tid; i < TB * NH; i += 256) cs[i] = io[(size_t)bt0 * NH + i];
  __syncthreads();

  float oga[4][5], a1a[4][5];
#pragma unroll
  for (int q = 0; q < 4; ++q)
#pragma unroll
    for (int j = 0; j < 5; ++j) { oga[q][j] = 0.f; a1a[q][j] = 0.f; }

  for (int h = 0; h < NH; ++h) {
    float cv[4];
#pragma unroll
    for (int q = 0; q < 4; ++q) cv[q] = cs[(rt + 8 * q) * NH + h];
#pragma unroll
    for (int j = 0; j < 5; ++j) {
      const float wg = oWg[h * NH + kl + 32 * j];
      const float w1 = oW1[h * NH + kl + 32 * j];
#pragma unroll
      for (int q = 0; q < 4; ++q) {
        oga[q][j] = fmaf(cv[q], wg, oga[q][j]);
        a1a[q][j] = fmaf(cv[q], w1, a1a[q][j]);
      }
    }
  }
#pragma unroll
  for (int q = 0; q < 4; ++q)
#pragma unroll
    for (int j = 0; j < 5; ++j) {
      const int k = kl + 32 * j;
      const float z = a1a[q][j] + ob1[k];
      oas[(rt + 8 * q) * NH + k] = z > 0.f ? z : expm1f(z);
    }
  __syncthreads();

  float o2a[4][5];
#pragma unroll
  for (int q = 0; q < 4; ++q)
#pragma unroll
    for (int j = 0; j < 5; ++j) o2a[q][j] = 0.f;
  for (int h = 0; h < NH; ++h) {
    float av[4];
#pragma unroll
    for (int q = 0; q < 4; ++q) av[q] = oas[(rt + 8 * q) * NH + h];
#pragma unroll
    for (int j = 0; j < 5; ++j) {
      const float w2v = oW2[h * NH + kl + 32 * j];
#pragma unroll
      for (int q = 0; q < 4; ++q) o2a[q][j] = fmaf(av[q], w2v, o2a[q][j]);
    }
  }
#pragma unroll
  for (int q = 0; q < 4; ++q) {
    const int row = rt + 8 * q;
    float feat[5];
    float s1 = 0.f;
#pragma unroll
    for (int j = 0; j < 5; ++j) {
      const int k = kl + 32 * j;
      const float oa2 = o2a[q][j] + ob2[k];
      const float zg = oga[q][j] + obg[k];
      const float g = 1.f / (1.f + expf(-zg));
      const float c = cs[row * NH + k];
      const float ft = fmaf(g, oa2 - c, c);
      feat[j] = ft;
      s1 += ft;
    }
    s1 = half_sum(s1);
    const float mean = s1 * (1.f / NH);
    float s2 = 0.f;
#pragma unroll
    for (int j = 0; j < 5; ++j) {
      const float d = feat[j] - mean;
      s2 = fmaf(d, d, s2);
    }
    s2 = half_sum(s2);
    const float inv = rsqrtf(s2 * (1.f / NH) + LN_EPS);
#pragma unroll
    for (int j = 0; j < 5; ++j) {
      const int k = kl + 32 * j;
      io[(size_t)(bt0 + row) * NH + k] =
          (feat[j] - mean) * inv * olng[k] + olnb[k];
    }
  }
}

extern "C" void kernel_launch(void* const* d_in, const int* in_sizes, int n_in,
                              void* d_out, int out_size, void* d_ws, size_t ws_size,
                              hipStream_t stream) {
  const float* x   = (const float*)d_in[0];
  const float* W1  = (const float*)d_in[1];
  const float* b1  = (const float*)d_in[2];
  const float* W2  = (const float*)d_in[3];
  const float* b2  = (const float*)d_in[4];
  const float* Wg  = (const float*)d_in[5];
  const float* bg  = (const float*)d_in[6];
  const float* lng = (const float*)d_in[7];
  const float* lnb = (const float*)d_in[8];
  const float* Ww  = (const float*)d_in[9];
  const float* bw  = (const float*)d_in[10];
  const float* oW1 = (const float*)d_in[11];
  const float* ob1 = (const float*)d_in[12];
  const float* oW2 = (const float*)d_in[13];
  const float* ob2 = (const float*)d_in[14];
  const float* oWg = (const float*)d_in[15];
  const float* obg = (const float*)d_in[16];
  const float* olng= (const float*)d_in[17];
  const float* olnb= (const float*)d_in[18];

  float* out  = (float*)d_out;
  float* wout = out + (size_t)NBT * NH;       // weights4 region of d_out
  unsigned short* w2t_g = (unsigned short*)d_ws;  // 32*160*168*2 = 1.72 MB

  k0_w2t<<<NF, 256, 0, stream>>>(W2, w2t_g);
  k1_weights<<<NB, 256, 0, stream>>>(x, Ww, bw, wout);
  k2_mfma<<<NBT / TB, 256, 0, stream>>>(x, W1, b1, w2t_g, b2, Wg, bg, lng, lnb,
                                        wout, out);
  k3_outgrn<<<NBT / TB, 256, 0, stream>>>(out, oW1, ob1, oW2, ob2, oWg, obg,
                                          olng, olnb);
}